// Round 18
// baseline (101.236 us; speedup 1.0000x reference)
//
#include <hip/hip_runtime.h>

// MMoE: B=16384 D=512 U=128 E=16 T=4, fp32 in/out.
// vs r17 (PASSING, 100.9us; moe 76.5 at 1 block/CU): moe BK 64->32 with
// full LDS double-buffer = 48KB total -> 2 blocks/CU at the same proven
// counted-vmcnt loop shape (vmcnt(3)+bar / MFMA / bar / STAGE kt+2).
// Swizzle: phys chunk = lhi^(llo>>2) (4-chunk rows), done via per-lane
// swizzled GLOBAL src + linear gload_lds dest (rule #21) -> prep writes
// xb/ekT PLAIN LINEAR (r12-proven bodies). K-order and all rounding
// points bit-identical to r12/r16/r17. Epilogue: r16 two-pass verbatim.
// ws: gates 4MiB @0, xb 16MiB @4MiB, ekT 2MiB @20MiB.

#define Bsz 16384
#define Dd  512
#define Uu  128
#define Ee  16
#define Tt  4
#define Nn  2048   // U*E

typedef short bf16x8 __attribute__((ext_vector_type(8)));
typedef float f32x4 __attribute__((ext_vector_type(4)));
typedef unsigned short u16x8 __attribute__((ext_vector_type(8)));

static __device__ __forceinline__ unsigned short f2bf(float f) {
    unsigned int u = __builtin_bit_cast(unsigned int, f);
    u += 0x7fffu + ((u >> 16) & 1u);   // round-to-nearest-even
    return (unsigned short)(u >> 16);
}
static __device__ __forceinline__ float bf2f(unsigned short s) {
    return __builtin_bit_cast(float, (unsigned int)s << 16);
}

#define GLOAD16(g, l) __builtin_amdgcn_global_load_lds( \
    (const __attribute__((address_space(1))) void*)(g), \
    (__attribute__((address_space(3))) void*)(l), 16, 0, 0)

// ---------------- Kernel A: prep = gates (+x->xb linear) U convert_ek ----------------
// blocks [0,1024): r12 gates verbatim (fused linear xb bf16 emission).
// blocks [1024,1280): r12 convert_ek verbatim (linear ekT [n][d]).
__global__ __launch_bounds__(256) void prep_kernel(
        const float* __restrict__ x, const float* __restrict__ gk,
        const float* __restrict__ gb, const float* __restrict__ ek,
        float* __restrict__ gates, unsigned short* __restrict__ xb,
        unsigned short* __restrict__ ekT) {
    __shared__ __align__(16) char pm[40960];
    const int tid = threadIdx.x;
    if (blockIdx.x >= 1024) {
        unsigned short* ts = (unsigned short*)pm;  // [64*65]
        const int b2 = blockIdx.x - 1024;
        const int n0 = (b2 & 31) * 64, d0 = (b2 >> 5) * 64;
        #pragma unroll
        for (int i = 0; i < 4; ++i) {
            int flat = i * 256 + tid;
            int dl = flat >> 4, ng = (flat & 15) * 4;
            const float4 v = *(const float4*)(ek + (size_t)(d0 + dl) * Nn + n0 + ng);
            ts[(ng + 0) * 65 + dl] = f2bf(v.x);
            ts[(ng + 1) * 65 + dl] = f2bf(v.y);
            ts[(ng + 2) * 65 + dl] = f2bf(v.z);
            ts[(ng + 3) * 65 + dl] = f2bf(v.w);
        }
        __syncthreads();
        #pragma unroll
        for (int i = 0; i < 4; ++i) {
            int flat = i * 256 + tid;
            int nl = flat >> 4, dg = (flat & 15) * 4;
            ushort4 w = make_ushort4(ts[nl * 65 + dg], ts[nl * 65 + dg + 1],
                                     ts[nl * 65 + dg + 2], ts[nl * 65 + dg + 3]);
            *(ushort4*)(ekT + (size_t)(n0 + nl) * Dd + d0 + dg) = w;
        }
        return;
    }
    float (*xl)[128] = (float (*)[128])pm;          // 8 KB
    float (*gkl)[64] = (float (*)[64])(pm + 8192);  // 32 KB
    const int w = tid >> 6, lane = tid & 63;
    const int b0 = blockIdx.x * 16;
    float acc[4] = {0.f, 0.f, 0.f, 0.f};

    for (int c = 0; c < 4; ++c) {
        const int d0 = c * 128;
        __syncthreads();  // previous chunk consumed
        #pragma unroll
        for (int p = 0; p < 2; ++p) {
            const int flat = p * 256 + tid;
            const int row = flat >> 5, c4 = (flat & 31) * 4;
            const float4 v =
                *(const float4*)(x + (size_t)(b0 + row) * Dd + d0 + c4);
            *(float4*)(&xl[row][c4]) = v;
            *(ushort4*)(xb + (size_t)(b0 + row) * Dd + d0 + c4) =
                make_ushort4(f2bf(v.x), f2bf(v.y), f2bf(v.z), f2bf(v.w));
        }
        {
            const int n = tid & 63, dl0 = tid >> 6;
            const float* gp = gk + (size_t)(n >> 4) * (Dd * Ee) + (n & 15)
                                 + (size_t)(d0 + dl0) * Ee;
            #pragma unroll
            for (int j = 0; j < 32; ++j)
                gkl[dl0 + j * 4][n] = gp[(size_t)j * 4 * Ee];
        }
        __syncthreads();
        #pragma unroll 4
        for (int dq = 0; dq < 32; ++dq) {
            float wv[4];
            #pragma unroll
            for (int q = 0; q < 4; ++q) wv[q] = gkl[dq * 4 + q][lane];
            #pragma unroll
            for (int r = 0; r < 4; ++r) {
                const float4 xv = *(const float4*)(&xl[w * 4 + r][dq * 4]);
                float a = acc[r];
                a = fmaf(xv.x, wv[0], a);
                a = fmaf(xv.y, wv[1], a);
                a = fmaf(xv.z, wv[2], a);
                a = fmaf(xv.w, wv[3], a);
                acc[r] = a;
            }
        }
    }
    const float bias = gb[lane];
    #pragma unroll
    for (int r = 0; r < 4; ++r) {
        float a = acc[r] + bias;
        float m = a;
        m = fmaxf(m, __shfl_xor(m, 1));
        m = fmaxf(m, __shfl_xor(m, 2));
        m = fmaxf(m, __shfl_xor(m, 4));
        m = fmaxf(m, __shfl_xor(m, 8));
        float p = __expf(a - m);
        float s = p;
        s += __shfl_xor(s, 1);
        s += __shfl_xor(s, 2);
        s += __shfl_xor(s, 4);
        s += __shfl_xor(s, 8);
        gates[(size_t)(b0 + w * 4 + r) * 64 + lane] = p / s;  // [b][t*16+e]
    }
}

// ---------------- Kernel B: expert GEMM + relu + gate contraction ----------------
// BK=32 counted-vmcnt dbuf pipeline; 48KB LDS -> 2 blocks/CU.
#define BM 128
#define BN 256
#define BK 32

__global__ __launch_bounds__(512) void moe_kernel(
        const unsigned short* __restrict__ xb,
        const unsigned short* __restrict__ ekT,
        const float* __restrict__ eb, const float* __restrict__ gates,
        float* __restrict__ out) {
    __shared__ __align__(64) char smem[49152];  // 2 bufs x (A 8K + B 16K)
    const int tid = threadIdx.x;
    const int wave = tid >> 6, lane = tid & 63;
    const int llo = lane & 15, lhi = lane >> 4;
    const int g = (blockIdx.x & 7) * 128 + (blockIdx.x >> 3);  // XCD swizzle
    const int b0 = (g >> 3) * BM;
    const int n0 = (g & 7) * BN;
    const int mr = (wave >> 2) * 64, nc = (wave & 3) * 64;
    f32x4 acc[4][4] = {};

// chunk c_: row = c_>>2, phys pos = c_&3 holds LOGICAL chunk (c_&3)^((row>>2)&3).
// Global src supplies that logical chunk; LDS dest stays linear (gload_lds).
#define STAGE(buf, kt_) do {                                                   \
    const int k0_ = (kt_) * BK;                                                \
    char* aB_ = smem + (buf) * 24576;                                          \
    char* bB_ = aB_ + 8192;                                                    \
    {   /* A: 512 chunks, 1/thread */                                          \
        const int c_ = tid;                                                    \
        const int r_ = c_ >> 2;                                                \
        const int lc_ = (c_ & 3) ^ ((r_ >> 2) & 3);                            \
        GLOAD16(xb + (size_t)(b0 + r_) * Dd + k0_ + lc_ * 8,                   \
                aB_ + (wave * 64) * 16);                                       \
    }                                                                          \
    _Pragma("unroll")                                                          \
    for (int i_ = 0; i_ < 2; ++i_) {  /* B: 1024 chunks, 2/thread */           \
        const int c_ = i_ * 512 + tid;                                         \
        const int r_ = c_ >> 2;                                                \
        const int lc_ = (c_ & 3) ^ ((r_ >> 2) & 3);                            \
        GLOAD16(ekT + (size_t)(n0 + r_) * Dd + k0_ + lc_ * 8,                  \
                bB_ + (i_ * 512 + wave * 64) * 16);                            \
    }                                                                          \
} while (0)

    STAGE(0, 0);
    STAGE(1, 1);
    for (int kt = 0; kt < Dd / BK; ++kt) {
        const int cur = kt & 1;
        // counted wait: the 3 loads of tile kt+1 stay in flight across the
        // barrier (never drain to 0 mid-loop). Single asm = code-motion fence.
        if (kt < 15) asm volatile("s_waitcnt vmcnt(3)\ns_barrier" ::: "memory");
        else         asm volatile("s_waitcnt vmcnt(0)\ns_barrier" ::: "memory");
        const char* aB = smem + cur * 24576;
        const char* bB = aB + 8192;
        {
            bf16x8 aF[4], bF[4];
            const int ph = (lhi ^ (llo >> 2)) << 4;  // phys 16B slot in 64B row
            #pragma unroll
            for (int mi = 0; mi < 4; ++mi)
                aF[mi] = *(const bf16x8*)(aB + (mr + mi * 16 + llo) * 64 + ph);
            #pragma unroll
            for (int ni = 0; ni < 4; ++ni)
                bF[ni] = *(const bf16x8*)(bB + (nc + ni * 16 + llo) * 64 + ph);
            #pragma unroll
            for (int mi = 0; mi < 4; ++mi)
                #pragma unroll
                for (int ni = 0; ni < 4; ++ni)
                    acc[mi][ni] = __builtin_amdgcn_mfma_f32_16x16x32_bf16(
                        aF[mi], bF[ni], acc[mi][ni], 0, 0, 0);
        }
        asm volatile("s_barrier" ::: "memory");  // all reads of buf[cur] done
        if (kt < 14) STAGE(cur, kt + 2);         // refill retired buffer
    }
    __syncthreads();

    // -------- two-pass epilogue (r16 verbatim): eo half [64][264] @ smem --------
    unsigned short* eoh = (unsigned short*)smem;
    #pragma unroll
    for (int pass = 0; pass < 2; ++pass) {
        __syncthreads();
        if ((mr >> 6) == pass) {
            #pragma unroll
            for (int ni = 0; ni < 4; ++ni) {
                const int col = nc + ni * 16 + llo;
                const float ebv = eb[n0 + col];
                #pragma unroll
                for (int mi = 0; mi < 4; ++mi)
                    #pragma unroll
                    for (int j = 0; j < 4; ++j) {
                        int rl = mi * 16 + lhi * 4 + j;
                        eoh[rl * 264 + col] = f2bf(fmaxf(acc[mi][ni][j] + ebv, 0.f));
                    }
            }
        }
        __syncthreads();
        #pragma unroll
        for (int i = 0; i < 2; ++i) {
            int f = i * 512 + tid;
            int ml = f >> 4, ul = f & 15;
            const unsigned short* er = eoh + ml * 264 + ul * 16;
            const int brow = b0 + pass * 64 + ml;
            const float* gr = gates + (size_t)brow * 64;
            float o0 = 0.f, o1 = 0.f, o2 = 0.f, o3 = 0.f;
            #pragma unroll
            for (int e = 0; e < 16; ++e) {
                float v = bf2f(er[e]);
                o0 = fmaf(v, gr[e], o0);
                o1 = fmaf(v, gr[16 + e], o1);
                o2 = fmaf(v, gr[32 + e], o2);
                o3 = fmaf(v, gr[48 + e], o3);
            }
            size_t base = (size_t)brow * Uu + (n0 >> 4) + ul;
            out[base] = o0;
            out[(size_t)Bsz * Uu + base] = o1;
            out[2 * (size_t)Bsz * Uu + base] = o2;
            out[3 * (size_t)Bsz * Uu + base] = o3;
        }
    }
#undef STAGE
}

extern "C" void kernel_launch(void* const* d_in, const int* in_sizes, int n_in,
                              void* d_out, int out_size, void* d_ws, size_t ws_size,
                              hipStream_t stream) {
    const float* x  = (const float*)d_in[0];
    const float* ek = (const float*)d_in[1];
    const float* eb = (const float*)d_in[2];
    const float* gk = (const float*)d_in[3];
    const float* gb = (const float*)d_in[4];
    float* out = (float*)d_out;

    char* wsb = (char*)d_ws;
    float* gates       = (float*)wsb;                            // 4 MiB @ 0
    unsigned short* xb  = (unsigned short*)(wsb + (4u << 20));   // 16 MiB @ 4
    unsigned short* ekT = (unsigned short*)(wsb + (20u << 20));  // 2 MiB @ 20

    prep_kernel<<<1280, 256, 0, stream>>>(x, gk, gb, ek, gates, xb, ekT);
    moe_kernel<<<1024, 512, 0, stream>>>(xb, ekT, eb, gates, out);
}

// Round 19
// 97.591 us; speedup vs baseline: 1.0374x; 1.0374x over previous
//
#include <hip/hip_runtime.h>

// MMoE: B=16384 D=512 U=128 E=16 T=4, fp32 in/out.
// Round 19 = best-of-proven combination (pure plumbing, no new logic):
//   prep_kernel: r18 VERBATIM (gates + fused x->xb bf16 + convert_ek in one
//     dispatch; passed r17/r18) — saves ~5us of launch gaps vs r12.
//   moe_kernel: r12 VERBATIM (best moe measured, 72.6us: reg-staged 2-phase,
//     T14 prefetch, XCD swizzle, LDA/LDB=72 padded LDS, fused epilogue).
// All computed values bit-identical to r12/r18 (both PASSING).
// ws: gates 4MiB @0, xb 16MiB @4MiB, ekT 2MiB @20MiB.

#define Bsz 16384
#define Dd  512
#define Uu  128
#define Ee  16
#define Tt  4
#define Nn  2048   // U*E

typedef short bf16x8 __attribute__((ext_vector_type(8)));
typedef float f32x4 __attribute__((ext_vector_type(4)));
typedef unsigned short u16x8 __attribute__((ext_vector_type(8)));

static __device__ __forceinline__ unsigned short f2bf(float f) {
    unsigned int u = __builtin_bit_cast(unsigned int, f);
    u += 0x7fffu + ((u >> 16) & 1u);   // round-to-nearest-even
    return (unsigned short)(u >> 16);
}
static __device__ __forceinline__ float bf2f(unsigned short s) {
    return __builtin_bit_cast(float, (unsigned int)s << 16);
}

// ---------------- Kernel A: prep = gates (+x->xb linear) U convert_ek ----------------
// blocks [0,1024): r12 gates verbatim (fused linear xb bf16 emission).
// blocks [1024,1280): r12 convert_ek verbatim (linear ekT [n][d]).
__global__ __launch_bounds__(256) void prep_kernel(
        const float* __restrict__ x, const float* __restrict__ gk,
        const float* __restrict__ gb, const float* __restrict__ ek,
        float* __restrict__ gates, unsigned short* __restrict__ xb,
        unsigned short* __restrict__ ekT) {
    __shared__ __align__(16) char pm[40960];
    const int tid = threadIdx.x;
    if (blockIdx.x >= 1024) {
        unsigned short* ts = (unsigned short*)pm;  // [64*65]
        const int b2 = blockIdx.x - 1024;
        const int n0 = (b2 & 31) * 64, d0 = (b2 >> 5) * 64;
        #pragma unroll
        for (int i = 0; i < 4; ++i) {
            int flat = i * 256 + tid;
            int dl = flat >> 4, ng = (flat & 15) * 4;
            const float4 v = *(const float4*)(ek + (size_t)(d0 + dl) * Nn + n0 + ng);
            ts[(ng + 0) * 65 + dl] = f2bf(v.x);
            ts[(ng + 1) * 65 + dl] = f2bf(v.y);
            ts[(ng + 2) * 65 + dl] = f2bf(v.z);
            ts[(ng + 3) * 65 + dl] = f2bf(v.w);
        }
        __syncthreads();
        #pragma unroll
        for (int i = 0; i < 4; ++i) {
            int flat = i * 256 + tid;
            int nl = flat >> 4, dg = (flat & 15) * 4;
            ushort4 w = make_ushort4(ts[nl * 65 + dg], ts[nl * 65 + dg + 1],
                                     ts[nl * 65 + dg + 2], ts[nl * 65 + dg + 3]);
            *(ushort4*)(ekT + (size_t)(n0 + nl) * Dd + d0 + dg) = w;
        }
        return;
    }
    float (*xl)[128] = (float (*)[128])pm;          // 8 KB
    float (*gkl)[64] = (float (*)[64])(pm + 8192);  // 32 KB
    const int w = tid >> 6, lane = tid & 63;
    const int b0 = blockIdx.x * 16;
    float acc[4] = {0.f, 0.f, 0.f, 0.f};

    for (int c = 0; c < 4; ++c) {
        const int d0 = c * 128;
        __syncthreads();  // previous chunk consumed
        #pragma unroll
        for (int p = 0; p < 2; ++p) {
            const int flat = p * 256 + tid;
            const int row = flat >> 5, c4 = (flat & 31) * 4;
            const float4 v =
                *(const float4*)(x + (size_t)(b0 + row) * Dd + d0 + c4);
            *(float4*)(&xl[row][c4]) = v;
            *(ushort4*)(xb + (size_t)(b0 + row) * Dd + d0 + c4) =
                make_ushort4(f2bf(v.x), f2bf(v.y), f2bf(v.z), f2bf(v.w));
        }
        {
            const int n = tid & 63, dl0 = tid >> 6;
            const float* gp = gk + (size_t)(n >> 4) * (Dd * Ee) + (n & 15)
                                 + (size_t)(d0 + dl0) * Ee;
            #pragma unroll
            for (int j = 0; j < 32; ++j)
                gkl[dl0 + j * 4][n] = gp[(size_t)j * 4 * Ee];
        }
        __syncthreads();
        #pragma unroll 4
        for (int dq = 0; dq < 32; ++dq) {
            float wv[4];
            #pragma unroll
            for (int q = 0; q < 4; ++q) wv[q] = gkl[dq * 4 + q][lane];
            #pragma unroll
            for (int r = 0; r < 4; ++r) {
                const float4 xv = *(const float4*)(&xl[w * 4 + r][dq * 4]);
                float a = acc[r];
                a = fmaf(xv.x, wv[0], a);
                a = fmaf(xv.y, wv[1], a);
                a = fmaf(xv.z, wv[2], a);
                a = fmaf(xv.w, wv[3], a);
                acc[r] = a;
            }
        }
    }
    const float bias = gb[lane];
    #pragma unroll
    for (int r = 0; r < 4; ++r) {
        float a = acc[r] + bias;
        float m = a;
        m = fmaxf(m, __shfl_xor(m, 1));
        m = fmaxf(m, __shfl_xor(m, 2));
        m = fmaxf(m, __shfl_xor(m, 4));
        m = fmaxf(m, __shfl_xor(m, 8));
        float p = __expf(a - m);
        float s = p;
        s += __shfl_xor(s, 1);
        s += __shfl_xor(s, 2);
        s += __shfl_xor(s, 4);
        s += __shfl_xor(s, 8);
        gates[(size_t)(b0 + w * 4 + r) * 64 + lane] = p / s;  // [b][t*16+e]
    }
}

// ---------------- Kernel B: expert GEMM + relu + gate contraction ----------------
// r12 moe VERBATIM: 128x256 tile, reg-staged 2-phase + T14 prefetch,
// XCD swizzle, padded LDS (LDA/LDB=72), single-pass fused epilogue.
#define BM 128
#define BN 256   // = 16 u's x 16 e's (n = u*16+e)
#define BK 64
#define LDA 72   // padded row stride (shorts); 144 B = multiple of 16 B
#define LDB 72
#define LDE 264

__global__ __launch_bounds__(512) void moe_kernel(
        const unsigned short* __restrict__ xb,
        const unsigned short* __restrict__ ekT,
        const float* __restrict__ eb, const float* __restrict__ gates,
        float* __restrict__ out) {
    __shared__ __align__(16) unsigned short smem[BM * LDE];
    unsigned short* sA = smem;             // [BM][LDA]  A tile, bf16
    unsigned short* sB = smem + BM * LDA;  // [BN][LDB]  B tile: sB[n][k]

    const int tid = threadIdx.x;
    const int wave = tid >> 6, lane = tid & 63;
    const int llo = lane & 15, lhi = lane >> 4;
    // XCD swizzle: bijective for 1024 blocks.
    const int g = (blockIdx.x & 7) * 128 + (blockIdx.x >> 3);
    const int b0 = (g >> 3) * BM;
    const int n0 = (g & 7) * BN;
    const int mr = (wave >> 2) * 64;  // wave row origin
    const int nc = (wave & 3) * 64;   // wave col origin

    f32x4 acc[4][4] = {};
    u16x8 va[2], vb[4];

    // prologue: load tile kt=0 into regs
    #pragma unroll
    for (int i = 0; i < 2; ++i) {
        int f = i * 512 + tid;
        va[i] = *(const u16x8*)(xb + (size_t)(b0 + (f >> 3)) * Dd + (f & 7) * 8);
    }
    #pragma unroll
    for (int i = 0; i < 4; ++i) {
        int f = i * 512 + tid;
        vb[i] = *(const u16x8*)(ekT + (size_t)(n0 + (f >> 3)) * Dd + (f & 7) * 8);
    }

    for (int kt = 0; kt < Dd / BK; ++kt) {
        __syncthreads();  // previous tile's MFMA reads done
        // ds_write current tile from regs
        #pragma unroll
        for (int i = 0; i < 2; ++i) {
            int f = i * 512 + tid;
            *(u16x8*)(sA + (f >> 3) * LDA + (f & 7) * 8) = va[i];
        }
        #pragma unroll
        for (int i = 0; i < 4; ++i) {
            int f = i * 512 + tid;
            *(u16x8*)(sB + (f >> 3) * LDB + (f & 7) * 8) = vb[i];
        }
        // T14: issue next tile's global loads; latency hides under MFMA phase
        if (kt < Dd / BK - 1) {
            const int k1 = (kt + 1) * BK;
            #pragma unroll
            for (int i = 0; i < 2; ++i) {
                int f = i * 512 + tid;
                va[i] = *(const u16x8*)(xb + (size_t)(b0 + (f >> 3)) * Dd + k1 + (f & 7) * 8);
            }
            #pragma unroll
            for (int i = 0; i < 4; ++i) {
                int f = i * 512 + tid;
                vb[i] = *(const u16x8*)(ekT + (size_t)(n0 + (f >> 3)) * Dd + k1 + (f & 7) * 8);
            }
        }
        __syncthreads();
        #pragma unroll
        for (int ks = 0; ks < BK; ks += 32) {
            bf16x8 aF[4], bF[4];
            #pragma unroll
            for (int mi = 0; mi < 4; ++mi)
                aF[mi] = *(const bf16x8*)(sA + (mr + mi * 16 + llo) * LDA + ks + lhi * 8);
            #pragma unroll
            for (int ni = 0; ni < 4; ++ni)
                bF[ni] = *(const bf16x8*)(sB + (nc + ni * 16 + llo) * LDB + ks + lhi * 8);
            #pragma unroll
            for (int mi = 0; mi < 4; ++mi)
                #pragma unroll
                for (int ni = 0; ni < 4; ++ni)
                    acc[mi][ni] = __builtin_amdgcn_mfma_f32_16x16x32_bf16(
                        aF[mi], bF[ni], acc[mi][ni], 0, 0, 0);
        }
    }

    __syncthreads();  // all MFMA reads done; safe to overlay eo on staging LDS
    unsigned short* eo = smem;  // [BM][LDE] bf16 expert tile (relu'd)
    #pragma unroll
    for (int ni = 0; ni < 4; ++ni) {
        const int col = nc + ni * 16 + llo;     // C frag: col = lane&15
        const float ebv = eb[n0 + col];         // flat [u][e] == n
        #pragma unroll
        for (int mi = 0; mi < 4; ++mi) {
            #pragma unroll
            for (int j = 0; j < 4; ++j) {
                int row = mr + mi * 16 + lhi * 4 + j;  // C frag: row = (lane>>4)*4+j
                eo[row * LDE + col] = f2bf(fmaxf(acc[mi][ni][j] + ebv, 0.f));
            }
        }
    }
    __syncthreads();
    // contraction: out[t,b,u] = sum_e eo[b,u,e] * gates[b][t*16+e]
    #pragma unroll
    for (int i = 0; i < 4; ++i) {
        int f = i * 512 + tid;
        int m = f >> 4, ul = f & 15;
        const unsigned short* er = eo + m * LDE + ul * 16;
        const float* gr = gates + (size_t)(b0 + m) * 64;
        float o0 = 0.f, o1 = 0.f, o2 = 0.f, o3 = 0.f;
        #pragma unroll
        for (int e = 0; e < 16; ++e) {
            float v = bf2f(er[e]);
            o0 = fmaf(v, gr[e], o0);
            o1 = fmaf(v, gr[16 + e], o1);
            o2 = fmaf(v, gr[32 + e], o2);
            o3 = fmaf(v, gr[48 + e], o3);
        }
        size_t base = (size_t)(b0 + m) * Uu + (n0 >> 4) + ul;
        out[base] = o0;
        out[(size_t)Bsz * Uu + base] = o1;
        out[2 * (size_t)Bsz * Uu + base] = o2;
        out[3 * (size_t)Bsz * Uu + base] = o3;
    }
}

extern "C" void kernel_launch(void* const* d_in, const int* in_sizes, int n_in,
                              void* d_out, int out_size, void* d_ws, size_t ws_size,
                              hipStream_t stream) {
    const float* x  = (const float*)d_in[0];
    const float* ek = (const float*)d_in[1];
    const float* eb = (const float*)d_in[2];
    const float* gk = (const float*)d_in[3];
    const float* gb = (const float*)d_in[4];
    float* out = (float*)d_out;

    char* wsb = (char*)d_ws;
    float* gates       = (float*)wsb;                            // 4 MiB @ 0
    unsigned short* xb  = (unsigned short*)(wsb + (4u << 20));   // 16 MiB @ 4
    unsigned short* ekT = (unsigned short*)(wsb + (20u << 20));  // 2 MiB @ 20

    prep_kernel<<<1280, 256, 0, stream>>>(x, gk, gb, ek, gates, xb, ekT);
    moe_kernel<<<1024, 512, 0, stream>>>(xb, ekT, eb, gates, out);
}

// Round 21
// 97.071 us; speedup vs baseline: 1.0429x; 1.0054x over previous
//
#include <hip/hip_runtime.h>

// MMoE: B=16384 D=512 U=128 E=16 T=4, fp32 in/out.
// vs r20 (value-correct but RACED on replay): 2-line sync fix. r20's
// mid-iteration vmcnt(2) had NO barrier -> other waves' QA1 (A-mh1 rows)
// loads could still be in flight when phases 1/3 read them. Fix: mid wait
// becomes vmcnt(2)+s_barrier (drains QA1(kt), FIFO=[QA1 x2, B1(kt+1) x2]);
// tail kt==7 uses vmcnt(0)+s_barrier (B1 not issued). Every LDS read now
// covered by issuing-wave drain before a shared barrier:
//   B,QA0(kt): top barrier (vmcnt(2) drains 6 of 8 oldest)
//   QA1(kt):  mid barrier
// 2 barriers per 64-MFMA K-step. All else r20 verbatim (values bit-identical
// to r12). prep_kernel: r19 VERBATIM.
// ws: gates 4MiB @0, xb 16MiB @4MiB, ekT 2MiB @20MiB.

#define Bsz 16384
#define Dd  512
#define Uu  128
#define Ee  16
#define Tt  4
#define Nn  2048   // U*E

typedef short bf16x8 __attribute__((ext_vector_type(8)));
typedef float f32x4 __attribute__((ext_vector_type(4)));
typedef unsigned short u16x8 __attribute__((ext_vector_type(8)));

static __device__ __forceinline__ unsigned short f2bf(float f) {
    unsigned int u = __builtin_bit_cast(unsigned int, f);
    u += 0x7fffu + ((u >> 16) & 1u);   // round-to-nearest-even
    return (unsigned short)(u >> 16);
}
static __device__ __forceinline__ float bf2f(unsigned short s) {
    return __builtin_bit_cast(float, (unsigned int)s << 16);
}

#define GLOAD16(g, l) __builtin_amdgcn_global_load_lds( \
    (const __attribute__((address_space(1))) void*)(g), \
    (__attribute__((address_space(3))) void*)(l), 16, 0, 0)

// ---------------- Kernel A: prep = gates (+x->xb linear) U convert_ek ----------------
// r19 VERBATIM.
__global__ __launch_bounds__(256) void prep_kernel(
        const float* __restrict__ x, const float* __restrict__ gk,
        const float* __restrict__ gb, const float* __restrict__ ek,
        float* __restrict__ gates, unsigned short* __restrict__ xb,
        unsigned short* __restrict__ ekT) {
    __shared__ __align__(16) char pm[40960];
    const int tid = threadIdx.x;
    if (blockIdx.x >= 1024) {
        unsigned short* ts = (unsigned short*)pm;  // [64*65]
        const int b2 = blockIdx.x - 1024;
        const int n0 = (b2 & 31) * 64, d0 = (b2 >> 5) * 64;
        #pragma unroll
        for (int i = 0; i < 4; ++i) {
            int flat = i * 256 + tid;
            int dl = flat >> 4, ng = (flat & 15) * 4;
            const float4 v = *(const float4*)(ek + (size_t)(d0 + dl) * Nn + n0 + ng);
            ts[(ng + 0) * 65 + dl] = f2bf(v.x);
            ts[(ng + 1) * 65 + dl] = f2bf(v.y);
            ts[(ng + 2) * 65 + dl] = f2bf(v.z);
            ts[(ng + 3) * 65 + dl] = f2bf(v.w);
        }
        __syncthreads();
        #pragma unroll
        for (int i = 0; i < 4; ++i) {
            int flat = i * 256 + tid;
            int nl = flat >> 4, dg = (flat & 15) * 4;
            ushort4 w = make_ushort4(ts[nl * 65 + dg], ts[nl * 65 + dg + 1],
                                     ts[nl * 65 + dg + 2], ts[nl * 65 + dg + 3]);
            *(ushort4*)(ekT + (size_t)(n0 + nl) * Dd + d0 + dg) = w;
        }
        return;
    }
    float (*xl)[128] = (float (*)[128])pm;          // 8 KB
    float (*gkl)[64] = (float (*)[64])(pm + 8192);  // 32 KB
    const int w = tid >> 6, lane = tid & 63;
    const int b0 = blockIdx.x * 16;
    float acc[4] = {0.f, 0.f, 0.f, 0.f};

    for (int c = 0; c < 4; ++c) {
        const int d0 = c * 128;
        __syncthreads();  // previous chunk consumed
        #pragma unroll
        for (int p = 0; p < 2; ++p) {
            const int flat = p * 256 + tid;
            const int row = flat >> 5, c4 = (flat & 31) * 4;
            const float4 v =
                *(const float4*)(x + (size_t)(b0 + row) * Dd + d0 + c4);
            *(float4*)(&xl[row][c4]) = v;
            *(ushort4*)(xb + (size_t)(b0 + row) * Dd + d0 + c4) =
                make_ushort4(f2bf(v.x), f2bf(v.y), f2bf(v.z), f2bf(v.w));
        }
        {
            const int n = tid & 63, dl0 = tid >> 6;
            const float* gp = gk + (size_t)(n >> 4) * (Dd * Ee) + (n & 15)
                                 + (size_t)(d0 + dl0) * Ee;
            #pragma unroll
            for (int j = 0; j < 32; ++j)
                gkl[dl0 + j * 4][n] = gp[(size_t)j * 4 * Ee];
        }
        __syncthreads();
        #pragma unroll 4
        for (int dq = 0; dq < 32; ++dq) {
            float wv[4];
            #pragma unroll
            for (int q = 0; q < 4; ++q) wv[q] = gkl[dq * 4 + q][lane];
            #pragma unroll
            for (int r = 0; r < 4; ++r) {
                const float4 xv = *(const float4*)(&xl[w * 4 + r][dq * 4]);
                float a = acc[r];
                a = fmaf(xv.x, wv[0], a);
                a = fmaf(xv.y, wv[1], a);
                a = fmaf(xv.z, wv[2], a);
                a = fmaf(xv.w, wv[3], a);
                acc[r] = a;
            }
        }
    }
    const float bias = gb[lane];
    #pragma unroll
    for (int r = 0; r < 4; ++r) {
        float a = acc[r] + bias;
        float m = a;
        m = fmaxf(m, __shfl_xor(m, 1));
        m = fmaxf(m, __shfl_xor(m, 2));
        m = fmaxf(m, __shfl_xor(m, 4));
        m = fmaxf(m, __shfl_xor(m, 8));
        float p = __expf(a - m);
        float s = p;
        s += __shfl_xor(s, 1);
        s += __shfl_xor(s, 2);
        s += __shfl_xor(s, 4);
        s += __shfl_xor(s, 8);
        gates[(size_t)(b0 + w * 4 + r) * 64 + lane] = p / s;  // [b][t*16+e]
    }
}

// ---------------- Kernel B: expert GEMM + relu + gate contraction ----------------
// 256x256 tile, 8 waves (2Mx4N, per-wave 128x64), BK=64, 128KB LDS dbuf.
#define BM 256
#define BN 256
#define BK 64

// stage B rows: CO=0 -> rows 0-127 (B-half1), CO=1024 -> rows 128-255 (B-half2)
#define ST_B(bufb, k1, CO) do { _Pragma("unroll")                               \
    for (int i_ = 0; i_ < 2; ++i_) {                                            \
        const int cb_ = i_ * 512 + wave * 64 + (CO);                            \
        const int q_ = cb_ + lane;                                              \
        GLOAD16(ekT + (size_t)(n0 + (q_ >> 3)) * Dd + (k1)                      \
                    + (((q_ & 7) ^ ((q_ >> 3) & 7)) * 8),                       \
                smem + (bufb) * 65536 + 32768 + cb_ * 16);                      \
    } } while (0)

// stage A 64-row group: CB=chunk base sel, RA=row add, CA=dest chunk add
#define ST_A1(bufb, k1, CB, RA, CA) {                                           \
    const int cb_ = (CB) + wave * 64;                                           \
    const int q_ = cb_ + lane;                                                  \
    GLOAD16(xb + (size_t)(b0 + (q_ >> 3) + (RA)) * Dd + (k1)                    \
               + (((q_ & 7) ^ ((q_ >> 3) & 7)) * 8),                            \
            smem + (bufb) * 65536 + (cb_ + (CA)) * 16); }
// QA0 = A rows {0-63, 128-191} (mh0 rows for wr=0 and wr=1)
#define ST_QA0(bufb, k1) { ST_A1(bufb, k1, 0, 0, 0) ST_A1(bufb, k1, 512, 64, 512) }
// QA1 = A rows {64-127, 192-255} (mh1 rows)
#define ST_QA1(bufb, k1) { ST_A1(bufb, k1, 0, 64, 512) ST_A1(bufb, k1, 512, 128, 1024) }

__global__ __launch_bounds__(512) void moe_kernel(
        const unsigned short* __restrict__ xb,
        const unsigned short* __restrict__ ekT,
        const float* __restrict__ eb, const float* __restrict__ gates,
        float* __restrict__ out) {
    __shared__ __align__(64) char smem[131072];  // buf k: A@k*65536 (32K), B@+32768
    const int tid = threadIdx.x;
    const int wave = tid >> 6, lane = tid & 63;
    const int llo = lane & 15, lhi = lane >> 4;
    const int wr = wave >> 2, wc = wave & 3;   // wave -> 128x64 output quadrant
    // XCD swizzle, bijective for 512 blocks (512%8==0)
    const int g = (blockIdx.x & 7) * 64 + (blockIdx.x >> 3);
    const int b0 = (g >> 3) * BM;
    const int n0 = (g & 7) * BN;
    f32x4 acc[8][4] = {};

    // prologue: stage kt=0 fully into buf0, deadline order B1,B2,QA0,QA1
    ST_B(0, 0, 0); ST_B(0, 0, 1024); ST_QA0(0, 0); ST_QA1(0, 0);

    for (int kt = 0; kt < Dd / BK; ++kt) {
        const int cur = kt & 1, nxt = cur ^ 1;
        const int k1 = (kt + 1) * BK;
        const char* aB = smem + cur * 65536;
        const char* bB = aB + 32768;
        // top barrier: FIFO has 8 loads of tile kt; vmcnt(2) drains the 6
        // oldest (B1,B2,QA0) in EVERY wave -> B and A-mh0 published.
        asm volatile("s_waitcnt vmcnt(2)\ns_barrier" ::: "memory");
        if (kt < 7) ST_B(nxt, k1, 0);
        bf16x8 bF[4];
        {   // phase 0: mh0 x ks0 (+ load bF ks0, held through phase 1)
            const int ph = (lhi ^ (llo & 7)) << 4;
            bf16x8 aF[4];
            #pragma unroll
            for (int ni = 0; ni < 4; ++ni)
                bF[ni] = *(const bf16x8*)(bB + (wc * 64 + ni * 16 + llo) * 128 + ph);
            #pragma unroll
            for (int k = 0; k < 4; ++k)
                aF[k] = *(const bf16x8*)(aB + (wr * 128 + k * 16 + llo) * 128 + ph);
            __builtin_amdgcn_s_setprio(1);
            #pragma unroll
            for (int k = 0; k < 4; ++k)
                #pragma unroll
                for (int ni = 0; ni < 4; ++ni)
                    acc[k][ni] = __builtin_amdgcn_mfma_f32_16x16x32_bf16(
                        aF[k], bF[ni], acc[k][ni], 0, 0, 0);
            __builtin_amdgcn_s_setprio(0);
        }
        // mid barrier (RACE FIX): drain own QA1(kt) then publish to all waves
        // before any mh1 read. kt<7: FIFO=[QA1 x2, B1(kt+1) x2] -> vmcnt(2);
        // kt==7: FIFO=[QA1 x2] only -> vmcnt(0).
        if (kt < 7) asm volatile("s_waitcnt vmcnt(2)\ns_barrier" ::: "memory");
        else        asm volatile("s_waitcnt vmcnt(0)\ns_barrier" ::: "memory");
        if (kt < 7) ST_B(nxt, k1, 1024);
        {   // phase 1: mh1 x ks0 (bF held)
            const int ph = (lhi ^ (llo & 7)) << 4;
            bf16x8 aF[4];
            #pragma unroll
            for (int k = 0; k < 4; ++k)
                aF[k] = *(const bf16x8*)(aB + (wr * 128 + 64 + k * 16 + llo) * 128 + ph);
            __builtin_amdgcn_s_setprio(1);
            #pragma unroll
            for (int k = 0; k < 4; ++k)
                #pragma unroll
                for (int ni = 0; ni < 4; ++ni)
                    acc[4 + k][ni] = __builtin_amdgcn_mfma_f32_16x16x32_bf16(
                        aF[k], bF[ni], acc[4 + k][ni], 0, 0, 0);
            __builtin_amdgcn_s_setprio(0);
        }
        if (kt < 7) ST_QA0(nxt, k1);
        {   // phase 2: mh0 x ks1 (re-read bF at ks1)
            const int ph = ((4 + lhi) ^ (llo & 7)) << 4;
            bf16x8 aF[4];
            #pragma unroll
            for (int ni = 0; ni < 4; ++ni)
                bF[ni] = *(const bf16x8*)(bB + (wc * 64 + ni * 16 + llo) * 128 + ph);
            #pragma unroll
            for (int k = 0; k < 4; ++k)
                aF[k] = *(const bf16x8*)(aB + (wr * 128 + k * 16 + llo) * 128 + ph);
            __builtin_amdgcn_s_setprio(1);
            #pragma unroll
            for (int k = 0; k < 4; ++k)
                #pragma unroll
                for (int ni = 0; ni < 4; ++ni)
                    acc[k][ni] = __builtin_amdgcn_mfma_f32_16x16x32_bf16(
                        aF[k], bF[ni], acc[k][ni], 0, 0, 0);
            __builtin_amdgcn_s_setprio(0);
        }
        if (kt < 7) ST_QA1(nxt, k1);
        {   // phase 3: mh1 x ks1
            const int ph = ((4 + lhi) ^ (llo & 7)) << 4;
            bf16x8 aF[4];
            #pragma unroll
            for (int k = 0; k < 4; ++k)
                aF[k] = *(const bf16x8*)(aB + (wr * 128 + 64 + k * 16 + llo) * 128 + ph);
            __builtin_amdgcn_s_setprio(1);
            #pragma unroll
            for (int k = 0; k < 4; ++k)
                #pragma unroll
                for (int ni = 0; ni < 4; ++ni)
                    acc[4 + k][ni] = __builtin_amdgcn_mfma_f32_16x16x32_bf16(
                        aF[k], bF[ni], acc[4 + k][ni], 0, 0, 0);
            __builtin_amdgcn_s_setprio(0);
        }
    }
    __syncthreads();  // full drain (vmcnt/lgkm 0) before overlaying LDS

    // -------- two-pass epilogue: eo half [128][264] overlays smem --------
    // tasks per pass: 128 rows x 16 u = 2048 over 512 threads = 4 each.
    unsigned short* eoh = (unsigned short*)smem;
    #pragma unroll
    for (int pass = 0; pass < 2; ++pass) {
        __syncthreads();
        if (wr == pass) {  // waves owning rows pass*128..+127 write their acc
            #pragma unroll
            for (int ni = 0; ni < 4; ++ni) {
                const int col = wc * 64 + ni * 16 + llo;
                const float ebv = eb[n0 + col];
                #pragma unroll
                for (int mi = 0; mi < 8; ++mi)
                    #pragma unroll
                    for (int j = 0; j < 4; ++j) {
                        const int rl = mi * 16 + lhi * 4 + j;  // local row 0..127
                        eoh[rl * 264 + col] = f2bf(fmaxf(acc[mi][ni][j] + ebv, 0.f));
                    }
            }
        }
        __syncthreads();
        #pragma unroll
        for (int i = 0; i < 4; ++i) {
            const int f = i * 512 + tid;        // [0,2048)
            const int ml = f >> 4, ul = f & 15;
            const unsigned short* er = eoh + ml * 264 + ul * 16;
            const int brow = b0 + pass * 128 + ml;
            const float* gr = gates + (size_t)brow * 64;
            float o0 = 0.f, o1 = 0.f, o2 = 0.f, o3 = 0.f;
            #pragma unroll
            for (int e = 0; e < 16; ++e) {
                const float v = bf2f(er[e]);
                o0 = fmaf(v, gr[e], o0);
                o1 = fmaf(v, gr[16 + e], o1);
                o2 = fmaf(v, gr[32 + e], o2);
                o3 = fmaf(v, gr[48 + e], o3);
            }
            const size_t base = (size_t)brow * Uu + (n0 >> 4) + ul;
            out[base] = o0;
            out[(size_t)Bsz * Uu + base] = o1;
            out[2 * (size_t)Bsz * Uu + base] = o2;
            out[3 * (size_t)Bsz * Uu + base] = o3;
        }
    }
}

extern "C" void kernel_launch(void* const* d_in, const int* in_sizes, int n_in,
                              void* d_out, int out_size, void* d_ws, size_t ws_size,
                              hipStream_t stream) {
    const float* x  = (const float*)d_in[0];
    const float* ek = (const float*)d_in[1];
    const float* eb = (const float*)d_in[2];
    const float* gk = (const float*)d_in[3];
    const float* gb = (const float*)d_in[4];
    float* out = (float*)d_out;

    char* wsb = (char*)d_ws;
    float* gates       = (float*)wsb;                            // 4 MiB @ 0
    unsigned short* xb  = (unsigned short*)(wsb + (4u << 20));   // 16 MiB @ 4
    unsigned short* ekT = (unsigned short*)(wsb + (20u << 20));  // 2 MiB @ 20

    prep_kernel<<<1280, 256, 0, stream>>>(x, gk, gb, ek, gates, xb, ekT);
    moe_kernel<<<(Bsz / BM) * (Nn / BN), 512, 0, stream>>>(xb, ekT, eb, gates, out);
}

// Round 22
// 91.260 us; speedup vs baseline: 1.1093x; 1.0637x over previous
//
#include <hip/hip_runtime.h>

// MMoE: B=16384 D=512 U=128 E=16 T=4, fp32 in/out.
// vs r21 (PASSING but 256^2 tile blocked at 1 block/CU by acc VGPRs):
// moe = r12 GEOMETRY (128x256, 8 waves, acc 4x4=64 VGPR) + proven pipeline
// pieces: BK=32 triple-buffer LDS (3x24KB=72KB -> 2 blocks/CU), gload_lds
// with r18-PASSED swizzle pair (src: chunk l=p^((row>>2)&3); read:
// ph=(lhi^(llo>>2))<<4; 2-way=free), ONE counted vmcnt(3)+s_barrier per
// K-step (r17/r21 asm idiom), depth-2 prefetch, T5 setprio. K-order
// bit-identical to r12 -> absmax unchanged. Epilogue r12 verbatim.
// prep_kernel r19 VERBATIM. ws: gates 4MiB @0, xb 16MiB @4, ekT 2MiB @20.

#define Bsz 16384
#define Dd  512
#define Uu  128
#define Ee  16
#define Tt  4
#define Nn  2048   // U*E

typedef short bf16x8 __attribute__((ext_vector_type(8)));
typedef float f32x4 __attribute__((ext_vector_type(4)));
typedef unsigned short u16x8 __attribute__((ext_vector_type(8)));

static __device__ __forceinline__ unsigned short f2bf(float f) {
    unsigned int u = __builtin_bit_cast(unsigned int, f);
    u += 0x7fffu + ((u >> 16) & 1u);   // round-to-nearest-even
    return (unsigned short)(u >> 16);
}
static __device__ __forceinline__ float bf2f(unsigned short s) {
    return __builtin_bit_cast(float, (unsigned int)s << 16);
}

#define GLOAD16(g, l) __builtin_amdgcn_global_load_lds( \
    (const __attribute__((address_space(1))) void*)(g), \
    (__attribute__((address_space(3))) void*)(l), 16, 0, 0)

// ---------------- Kernel A: prep = gates (+x->xb linear) U convert_ek ----------------
// r19 VERBATIM.
__global__ __launch_bounds__(256) void prep_kernel(
        const float* __restrict__ x, const float* __restrict__ gk,
        const float* __restrict__ gb, const float* __restrict__ ek,
        float* __restrict__ gates, unsigned short* __restrict__ xb,
        unsigned short* __restrict__ ekT) {
    __shared__ __align__(16) char pm[40960];
    const int tid = threadIdx.x;
    if (blockIdx.x >= 1024) {
        unsigned short* ts = (unsigned short*)pm;  // [64*65]
        const int b2 = blockIdx.x - 1024;
        const int n0 = (b2 & 31) * 64, d0 = (b2 >> 5) * 64;
        #pragma unroll
        for (int i = 0; i < 4; ++i) {
            int flat = i * 256 + tid;
            int dl = flat >> 4, ng = (flat & 15) * 4;
            const float4 v = *(const float4*)(ek + (size_t)(d0 + dl) * Nn + n0 + ng);
            ts[(ng + 0) * 65 + dl] = f2bf(v.x);
            ts[(ng + 1) * 65 + dl] = f2bf(v.y);
            ts[(ng + 2) * 65 + dl] = f2bf(v.z);
            ts[(ng + 3) * 65 + dl] = f2bf(v.w);
        }
        __syncthreads();
        #pragma unroll
        for (int i = 0; i < 4; ++i) {
            int flat = i * 256 + tid;
            int nl = flat >> 4, dg = (flat & 15) * 4;
            ushort4 w = make_ushort4(ts[nl * 65 + dg], ts[nl * 65 + dg + 1],
                                     ts[nl * 65 + dg + 2], ts[nl * 65 + dg + 3]);
            *(ushort4*)(ekT + (size_t)(n0 + nl) * Dd + d0 + dg) = w;
        }
        return;
    }
    float (*xl)[128] = (float (*)[128])pm;          // 8 KB
    float (*gkl)[64] = (float (*)[64])(pm + 8192);  // 32 KB
    const int w = tid >> 6, lane = tid & 63;
    const int b0 = blockIdx.x * 16;
    float acc[4] = {0.f, 0.f, 0.f, 0.f};

    for (int c = 0; c < 4; ++c) {
        const int d0 = c * 128;
        __syncthreads();  // previous chunk consumed
        #pragma unroll
        for (int p = 0; p < 2; ++p) {
            const int flat = p * 256 + tid;
            const int row = flat >> 5, c4 = (flat & 31) * 4;
            const float4 v =
                *(const float4*)(x + (size_t)(b0 + row) * Dd + d0 + c4);
            *(float4*)(&xl[row][c4]) = v;
            *(ushort4*)(xb + (size_t)(b0 + row) * Dd + d0 + c4) =
                make_ushort4(f2bf(v.x), f2bf(v.y), f2bf(v.z), f2bf(v.w));
        }
        {
            const int n = tid & 63, dl0 = tid >> 6;
            const float* gp = gk + (size_t)(n >> 4) * (Dd * Ee) + (n & 15)
                                 + (size_t)(d0 + dl0) * Ee;
            #pragma unroll
            for (int j = 0; j < 32; ++j)
                gkl[dl0 + j * 4][n] = gp[(size_t)j * 4 * Ee];
        }
        __syncthreads();
        #pragma unroll 4
        for (int dq = 0; dq < 32; ++dq) {
            float wv[4];
            #pragma unroll
            for (int q = 0; q < 4; ++q) wv[q] = gkl[dq * 4 + q][lane];
            #pragma unroll
            for (int r = 0; r < 4; ++r) {
                const float4 xv = *(const float4*)(&xl[w * 4 + r][dq * 4]);
                float a = acc[r];
                a = fmaf(xv.x, wv[0], a);
                a = fmaf(xv.y, wv[1], a);
                a = fmaf(xv.z, wv[2], a);
                a = fmaf(xv.w, wv[3], a);
                acc[r] = a;
            }
        }
    }
    const float bias = gb[lane];
    #pragma unroll
    for (int r = 0; r < 4; ++r) {
        float a = acc[r] + bias;
        float m = a;
        m = fmaxf(m, __shfl_xor(m, 1));
        m = fmaxf(m, __shfl_xor(m, 2));
        m = fmaxf(m, __shfl_xor(m, 4));
        m = fmaxf(m, __shfl_xor(m, 8));
        float p = __expf(a - m);
        float s = p;
        s += __shfl_xor(s, 1);
        s += __shfl_xor(s, 2);
        s += __shfl_xor(s, 4);
        s += __shfl_xor(s, 8);
        gates[(size_t)(b0 + w * 4 + r) * 64 + lane] = p / s;  // [b][t*16+e]
    }
}

// ---------------- Kernel B: expert GEMM + relu + gate contraction ----------------
// 128x256, 8 waves, BK=32, triple-buffer 72KB, counted vmcnt(3), gload_lds.
#define BM 128
#define BN 256
#define BK 32

// src pre-swizzle (r18-PASSED pair): phys chunk p of row r holds logical
// chunk l = p ^ ((r>>2)&3); read uses ph = (lhi ^ (llo>>2))<<4.
#define ST_A(buf, kt_) {                                                        \
    const int c_ = wave * 64 + lane;                                            \
    const int r_ = c_ >> 2;                                                     \
    const int l_ = (c_ & 3) ^ ((r_ >> 2) & 3);                                  \
    GLOAD16(xb + (size_t)(b0 + r_) * Dd + (kt_) * BK + l_ * 8,                  \
            smem + (buf) * 24576 + c_ * 16); }
#define ST_B(buf, kt_) { _Pragma("unroll")                                      \
    for (int i_ = 0; i_ < 2; ++i_) {                                            \
        const int c_ = i_ * 512 + wave * 64 + lane;                             \
        const int r_ = c_ >> 2;                                                 \
        const int l_ = (c_ & 3) ^ ((r_ >> 2) & 3);                              \
        GLOAD16(ekT + (size_t)(n0 + r_) * Dd + (kt_) * BK + l_ * 8,             \
                smem + (buf) * 24576 + 8192 + c_ * 16); } }
#define STAGE(buf, kt_) { ST_A(buf, kt_) ST_B(buf, kt_) }  // 3 loads/wave

__global__ __launch_bounds__(512) void moe_kernel(
        const unsigned short* __restrict__ xb,
        const unsigned short* __restrict__ ekT,
        const float* __restrict__ eb, const float* __restrict__ gates,
        float* __restrict__ out) {
    __shared__ __align__(64) char smem[73728];  // 3 bufs x (A 8K + B 16K)
    const int tid = threadIdx.x;
    const int wave = tid >> 6, lane = tid & 63;
    const int llo = lane & 15, lhi = lane >> 4;
    const int g = (blockIdx.x & 7) * 128 + (blockIdx.x >> 3);  // XCD swizzle
    const int b0 = (g >> 3) * BM;
    const int n0 = (g & 7) * BN;
    const int mr = (wave >> 2) * 64, nc = (wave & 3) * 64;
    f32x4 acc[4][4] = {};

    STAGE(0, 0);
    STAGE(1, 1);
    for (int kt = 0; kt < Dd / BK; ++kt) {
        const char* aB = smem + (kt % 3) * 24576;
        const char* bB = aB + 8192;
        // counted wait: own 3 oldest loads (tile kt) drain; tile kt+1's 3
        // stay in flight across the barrier. Barrier publishes to all waves.
        if (kt < 15) asm volatile("s_waitcnt vmcnt(3)\ns_barrier" ::: "memory");
        else         asm volatile("s_waitcnt vmcnt(0)\ns_barrier" ::: "memory");
        if (kt < 14) STAGE((kt + 2) % 3, kt + 2);  // buf last read in kt-1
        {
            const int ph = (lhi ^ (llo >> 2)) << 4;
            bf16x8 aF[4], bF[4];
            #pragma unroll
            for (int mi = 0; mi < 4; ++mi)
                aF[mi] = *(const bf16x8*)(aB + (mr + mi * 16 + llo) * 64 + ph);
            #pragma unroll
            for (int ni = 0; ni < 4; ++ni)
                bF[ni] = *(const bf16x8*)(bB + (nc + ni * 16 + llo) * 64 + ph);
            __builtin_amdgcn_s_setprio(1);
            #pragma unroll
            for (int mi = 0; mi < 4; ++mi)
                #pragma unroll
                for (int ni = 0; ni < 4; ++ni)
                    acc[mi][ni] = __builtin_amdgcn_mfma_f32_16x16x32_bf16(
                        aF[mi], bF[ni], acc[mi][ni], 0, 0, 0);
            __builtin_amdgcn_s_setprio(0);
        }
    }
    __syncthreads();  // all reads done; safe to overlay eo on staging LDS

    // -------- epilogue: r12 VERBATIM (eo [128][264] overlay, fused contraction) --------
    unsigned short* eo = (unsigned short*)smem;
    #pragma unroll
    for (int ni = 0; ni < 4; ++ni) {
        const int col = nc + ni * 16 + llo;
        const float ebv = eb[n0 + col];
        #pragma unroll
        for (int mi = 0; mi < 4; ++mi) {
            #pragma unroll
            for (int j = 0; j < 4; ++j) {
                int row = mr + mi * 16 + lhi * 4 + j;
                eo[row * 264 + col] = f2bf(fmaxf(acc[mi][ni][j] + ebv, 0.f));
            }
        }
    }
    __syncthreads();
    #pragma unroll
    for (int i = 0; i < 4; ++i) {
        int f = i * 512 + tid;
        int m = f >> 4, ul = f & 15;
        const unsigned short* er = eo + m * 264 + ul * 16;
        const float* gr = gates + (size_t)(b0 + m) * 64;
        float o0 = 0.f, o1 = 0.f, o2 = 0.f, o3 = 0.f;
        #pragma unroll
        for (int e = 0; e < 16; ++e) {
            float v = bf2f(er[e]);
            o0 = fmaf(v, gr[e], o0);
            o1 = fmaf(v, gr[16 + e], o1);
            o2 = fmaf(v, gr[32 + e], o2);
            o3 = fmaf(v, gr[48 + e], o3);
        }
        size_t base = (size_t)(b0 + m) * Uu + (n0 >> 4) + ul;
        out[base] = o0;
        out[(size_t)Bsz * Uu + base] = o1;
        out[2 * (size_t)Bsz * Uu + base] = o2;
        out[3 * (size_t)Bsz * Uu + base] = o3;
    }
}

extern "C" void kernel_launch(void* const* d_in, const int* in_sizes, int n_in,
                              void* d_out, int out_size, void* d_ws, size_t ws_size,
                              hipStream_t stream) {
    const float* x  = (const float*)d_in[0];
    const float* ek = (const float*)d_in[1];
    const float* eb = (const float*)d_in[2];
    const float* gk = (const float*)d_in[3];
    const float* gb = (const float*)d_in[4];
    float* out = (float*)d_out;

    char* wsb = (char*)d_ws;
    float* gates       = (float*)wsb;                            // 4 MiB @ 0
    unsigned short* xb  = (unsigned short*)(wsb + (4u << 20));   // 16 MiB @ 4
    unsigned short* ekT = (unsigned short*)(wsb + (20u << 20));  // 2 MiB @ 20

    prep_kernel<<<1280, 256, 0, stream>>>(x, gk, gb, ek, gates, xb, ekT);
    moe_kernel<<<(Bsz / BM) * (Nn / BN), 512, 0, stream>>>(xb, ekT, eb, gates, out);
}